// Round 1
// baseline (420.998 us; speedup 1.0000x reference)
//
#include <hip/hip_runtime.h>

// Problem constants
#define SRC_N   (512 * 512)        // gaussians per batch = 262144
#define IMG_W   1024
#define IMG_HW  (1024 * 1024)
#define BATCH   4

// ---------------------------------------------------------------------------
// Scatter kernel: one thread per gaussian.
// Reads channels {0,1} of position_map and {0,1,10,11,12,13} of uv_maps
// (all coalesced: consecutive threads -> consecutive n within a channel).
// Atomically accumulates color*opacity into out[b, c, py, px].
// Corner pixels (both coords clamped) receive ~5.8% of ALL points each ->
// aggregated in LDS per block, one global atomic per corner-channel per block.
// ---------------------------------------------------------------------------
__global__ void __launch_bounds__(256)
scatter_kernel(const float* __restrict__ uv,
               const float* __restrict__ pos,
               float* __restrict__ out) {
    const int gid = blockIdx.x * blockDim.x + threadIdx.x;
    const int b = gid >> 18;            // / SRC_N
    const int n = gid & (SRC_N - 1);    // % SRC_N

    const float* uvb = uv  + (size_t)b * 14 * SRC_N;
    const float* pb  = pos + (size_t)b * 3  * SRC_N;

    // positions (z is never used by the reference renderer)
    const float posx = pb[n]         + uvb[n];
    const float posy = pb[SRC_N + n] + uvb[SRC_N + n];

    // opacity = sigmoid(uv[10])
    const float o    = uvb[10 * SRC_N + n];
    const float opac = 1.0f / (1.0f + expf(-o));

    const float r  = uvb[11 * SRC_N + n] * opac;
    const float g  = uvb[12 * SRC_N + n] * opac;
    const float bl = uvb[13 * SRC_N + n] * opac;

    // truncating cast (matches .astype(int32)), then clamp (matches jnp.clip)
    int px = (int)((posx + 1.0f) * 512.0f);
    int py = (int)((posy + 1.0f) * 512.0f);
    px = min(max(px, 0), IMG_W - 1);
    py = min(max(py, 0), IMG_W - 1);
    const int idx = py * IMG_W + px;

    const size_t ob = (size_t)b * 3 * IMG_HW;

    // per-block corner accumulator: 4 corners x 3 channels
    __shared__ float sc[12];
    if (threadIdx.x < 12) sc[threadIdx.x] = 0.0f;
    __syncthreads();

    const bool xe = (px == 0) | (px == IMG_W - 1);
    const bool ye = (py == 0) | (py == IMG_W - 1);
    if (xe & ye) {
        const int ci = ((py != 0) ? 2 : 0) + ((px != 0) ? 1 : 0);
        atomicAdd(&sc[ci * 3 + 0], r);
        atomicAdd(&sc[ci * 3 + 1], g);
        atomicAdd(&sc[ci * 3 + 2], bl);
    } else {
        atomicAdd(&out[ob + 0 * IMG_HW + idx], r);
        atomicAdd(&out[ob + 1 * IMG_HW + idx], g);
        atomicAdd(&out[ob + 2 * IMG_HW + idx], bl);
    }
    __syncthreads();

    if (threadIdx.x < 12) {
        const float v = sc[threadIdx.x];
        if (v != 0.0f) {
            const int ci = threadIdx.x / 3;
            const int c  = threadIdx.x % 3;
            const int corner_idx[4] = {0, IMG_W - 1,
                                       (IMG_W - 1) * IMG_W,
                                       (IMG_W - 1) * IMG_W + IMG_W - 1};
            atomicAdd(&out[ob + (size_t)c * IMG_HW + corner_idx[ci]], v);
        }
    }
}

// ---------------------------------------------------------------------------
// Clip kernel: out = clip(out, 0, 1), vectorized float4.
// ---------------------------------------------------------------------------
__global__ void __launch_bounds__(256)
clip_kernel(float4* __restrict__ out, int n4) {
    const int i = blockIdx.x * blockDim.x + threadIdx.x;
    if (i < n4) {
        float4 v = out[i];
        v.x = fminf(fmaxf(v.x, 0.0f), 1.0f);
        v.y = fminf(fmaxf(v.y, 0.0f), 1.0f);
        v.z = fminf(fmaxf(v.z, 0.0f), 1.0f);
        v.w = fminf(fmaxf(v.w, 0.0f), 1.0f);
        out[i] = v;
    }
}

extern "C" void kernel_launch(void* const* d_in, const int* in_sizes, int n_in,
                              void* d_out, int out_size, void* d_ws, size_t ws_size,
                              hipStream_t stream) {
    const float* uv  = (const float*)d_in[0];   // (4,14,512,512)
    const float* pos = (const float*)d_in[1];   // (4,3,512,512)
    float* out = (float*)d_out;                 // (4,3,1024,1024)

    // d_out is poisoned to 0xAA before every timed launch: zero it ourselves.
    hipMemsetAsync(d_out, 0, (size_t)out_size * sizeof(float), stream);

    const int total = BATCH * SRC_N;            // 1,048,576 threads
    scatter_kernel<<<total / 256, 256, 0, stream>>>(uv, pos, out);

    const int n4 = out_size / 4;                // 3,145,728 float4s
    clip_kernel<<<(n4 + 255) / 256, 256, 0, stream>>>((float4*)out, n4);
}

// Round 2
// 254.076 us; speedup vs baseline: 1.6570x; 1.6570x over previous
//
#include <hip/hip_runtime.h>

// Problem constants
#define SRC_N   (512 * 512)        // gaussians per batch = 262144
#define IMG_W   1024
#define IMG_HW  (1024 * 1024)
#define BATCH   4
#define BSLOTS  4096               // boundary slots per (b,c): top|bottom|left|right
#define BSTRIDE (BATCH * 3 * BSLOTS)   // floats per replica = 49152

// ---------------------------------------------------------------------------
// Scatter. One thread per gaussian. Boundary pixels (px or py in {0,1023})
// receive 73% of all points -> accumulate into R privatized replica buffers
// in ws to break same-address atomic chains. Corners additionally aggregated
// per-block in LDS (they alone get 23% of all points). Interior pixels
// (~0.08 expected hits each) use direct atomics to the framebuffer.
// ---------------------------------------------------------------------------
__global__ void __launch_bounds__(256)
scatter_kernel(const float* __restrict__ uv,
               const float* __restrict__ pos,
               float* __restrict__ out,
               float* __restrict__ repl,
               int rmask) {
    const int gid = blockIdx.x * blockDim.x + threadIdx.x;
    const int b = gid >> 18;            // / SRC_N  (uniform per block)
    const int n = gid & (SRC_N - 1);    // % SRC_N

    const float* uvb = uv  + (size_t)b * 14 * SRC_N;
    const float* pb  = pos + (size_t)b * 3  * SRC_N;

    const float posx = pb[n]         + uvb[n];
    const float posy = pb[SRC_N + n] + uvb[SRC_N + n];

    const float o    = uvb[10 * SRC_N + n];
    const float opac = 1.0f / (1.0f + expf(-o));

    const float r  = uvb[11 * SRC_N + n] * opac;
    const float g  = uvb[12 * SRC_N + n] * opac;
    const float bl = uvb[13 * SRC_N + n] * opac;

    int px = (int)((posx + 1.0f) * 512.0f);   // truncating cast, then clamp
    int py = (int)((posy + 1.0f) * 512.0f);
    px = min(max(px, 0), IMG_W - 1);
    py = min(max(py, 0), IMG_W - 1);

    // replica base for this block's batch (uniform per block)
    float* rb = repl + (size_t)(blockIdx.x & rmask) * BSTRIDE + (size_t)b * 3 * BSLOTS;

    __shared__ float sc[12];                  // 4 corners x 3 channels
    if (threadIdx.x < 12) sc[threadIdx.x] = 0.0f;
    __syncthreads();

    const bool xe = (px == 0) | (px == IMG_W - 1);
    const bool ye = (py == 0) | (py == IMG_W - 1);

    if (xe & ye) {
        // corner: aggregate in LDS, flush once per block below
        const int ci = ((py != 0) ? 2 : 0) + ((px != 0) ? 1 : 0);
        atomicAdd(&sc[ci * 3 + 0], r);
        atomicAdd(&sc[ci * 3 + 1], g);
        atomicAdd(&sc[ci * 3 + 2], bl);
    } else if (ye) {
        // top/bottom row (non-corner)
        const int slot = (py == 0) ? px : (1024 + px);
        atomicAdd(&rb[0 * BSLOTS + slot], r);
        atomicAdd(&rb[1 * BSLOTS + slot], g);
        atomicAdd(&rb[2 * BSLOTS + slot], bl);
    } else if (xe) {
        // left/right column (non-corner)
        const int slot = (px == 0) ? (2048 + py) : (3072 + py);
        atomicAdd(&rb[0 * BSLOTS + slot], r);
        atomicAdd(&rb[1 * BSLOTS + slot], g);
        atomicAdd(&rb[2 * BSLOTS + slot], bl);
    } else {
        // interior: direct scatter, negligible contention
        const size_t ob = (size_t)b * 3 * IMG_HW;
        const int idx = py * IMG_W + px;
        atomicAdd(&out[ob + 0 * IMG_HW + idx], r);
        atomicAdd(&out[ob + 1 * IMG_HW + idx], g);
        atomicAdd(&out[ob + 2 * IMG_HW + idx], bl);
    }
    __syncthreads();

    if (threadIdx.x < 12) {
        const float v = sc[threadIdx.x];
        if (v != 0.0f) {
            const int ci = threadIdx.x / 3;
            const int c  = threadIdx.x % 3;
            // corner -> boundary slot: (0,0)->0 (0,1023)->1023 (1023,0)->1024 (1023,1023)->2047
            const int cslot[4] = {0, 1023, 1024, 2047};
            atomicAdd(&rb[c * BSLOTS + cslot[ci]], v);
        }
    }
}

// ---------------------------------------------------------------------------
// Reduce R replicas -> boundary pixels (direct store: interior path never
// touches boundary pixels). Skips the 4 unused left/right corner slots.
// ---------------------------------------------------------------------------
__global__ void __launch_bounds__(256)
boundary_reduce(const float* __restrict__ repl, float* __restrict__ out, int R) {
    const int t = blockIdx.x * blockDim.x + threadIdx.x;
    if (t >= BSTRIDE) return;

    float s = 0.0f;
    for (int r = 0; r < R; ++r) s += repl[(size_t)r * BSTRIDE + t];

    const int b   = t / (3 * BSLOTS);
    const int rem = t % (3 * BSLOTS);
    const int c   = rem / BSLOTS;
    const int e   = rem % BSLOTS;

    int px, py;
    if (e < 1024)      { py = 0;        px = e; }
    else if (e < 2048) { py = 1023;     px = e - 1024; }
    else if (e < 3072) { px = 0;        py = e - 2048; if (py == 0 || py == 1023) return; }
    else               { px = 1023;     py = e - 3072; if (py == 0 || py == 1023) return; }

    out[(size_t)b * 3 * IMG_HW + (size_t)c * IMG_HW + py * IMG_W + px] = s;
}

// ---------------------------------------------------------------------------
// Clip kernel: out = clip(out, 0, 1), vectorized float4.
// ---------------------------------------------------------------------------
__global__ void __launch_bounds__(256)
clip_kernel(float4* __restrict__ out, int n4) {
    const int i = blockIdx.x * blockDim.x + threadIdx.x;
    if (i < n4) {
        float4 v = out[i];
        v.x = fminf(fmaxf(v.x, 0.0f), 1.0f);
        v.y = fminf(fmaxf(v.y, 0.0f), 1.0f);
        v.z = fminf(fmaxf(v.z, 0.0f), 1.0f);
        v.w = fminf(fmaxf(v.w, 0.0f), 1.0f);
        out[i] = v;
    }
}

extern "C" void kernel_launch(void* const* d_in, const int* in_sizes, int n_in,
                              void* d_out, int out_size, void* d_ws, size_t ws_size,
                              hipStream_t stream) {
    const float* uv  = (const float*)d_in[0];   // (4,14,512,512)
    const float* pos = (const float*)d_in[1];   // (4,3,512,512)
    float* out  = (float*)d_out;                // (4,3,1024,1024)
    float* repl = (float*)d_ws;

    // replica count: largest power of 2 <= 64 that fits in ws
    const size_t repl_bytes = (size_t)BSTRIDE * sizeof(float);
    int R = 1;
    while (R * 2 <= 64 && (size_t)(R * 2) * repl_bytes <= ws_size) R *= 2;
    const int rmask = R - 1;

    hipMemsetAsync(d_out, 0, (size_t)out_size * sizeof(float), stream);
    hipMemsetAsync(d_ws, 0, (size_t)R * repl_bytes, stream);

    const int total = BATCH * SRC_N;            // 1,048,576 threads
    scatter_kernel<<<total / 256, 256, 0, stream>>>(uv, pos, out, repl, rmask);

    boundary_reduce<<<(BSTRIDE + 255) / 256, 256, 0, stream>>>(repl, out, R);

    const int n4 = out_size / 4;                // 3,145,728 float4s
    clip_kernel<<<(n4 + 255) / 256, 256, 0, stream>>>((float4*)out, n4);
}